// Round 12
// baseline (193.949 us; speedup 1.0000x reference)
//
#include <hip/hip_runtime.h>
#include <hip/hip_bf16.h>

// Problem constants
#define BB 2
#define SS 2048
#define CC 1024
#define HH 16
#define DDIM 64
#define NROWS (BB*SS)   // 4096

// q pre-scale: (1/sqrt(64)) / ln2  -> scores in log2 units, exp2 == exp
#define QSC 0.18033688011112042f

typedef __attribute__((ext_vector_type(8))) short bf16x8;   // 8 bf16 = 4 VGPR
typedef __attribute__((ext_vector_type(4))) float f32x4;

__device__ __forceinline__ f32x4 mfma16(bf16x8 a, bf16x8 b, f32x4 c) {
    return __builtin_amdgcn_mfma_f32_16x16x32_bf16(a, b, c, 0, 0, 0);
}

// ---------------------------------------------------------------------------
// prep_wt: W fp32 [g][k][n] -> bf16 W^T [z*4+g][n][k] via LDS tile transpose.
// ---------------------------------------------------------------------------
__global__ __launch_bounds__(256) void prep_wt(
    const float* __restrict__ wq, const float* __restrict__ wk,
    const float* __restrict__ wv, __hip_bfloat16* __restrict__ wt)
{
    const float* w = blockIdx.z == 0 ? wq : blockIdx.z == 1 ? wk : wv;
    const int g  = blockIdx.y;
    const int kt = blockIdx.x >> 2;
    const int nt = blockIdx.x & 3;
    __shared__ __hip_bfloat16 Ls[64][76];
    const int t = threadIdx.x;
    #pragma unroll
    for (int j = 0; j < 4; ++j) {
        int f4 = t + j*256;
        int row = f4 >> 4, n0 = (f4 & 15) * 4;
        float4 f = *(const float4*)&w[(size_t)g*65536 + (size_t)(kt*64+row)*256
                                      + nt*64 + n0];
        Ls[n0+0][row] = __float2bfloat16(f.x);
        Ls[n0+1][row] = __float2bfloat16(f.y);
        Ls[n0+2][row] = __float2bfloat16(f.z);
        Ls[n0+3][row] = __float2bfloat16(f.w);
    }
    __syncthreads();
    #pragma unroll
    for (int j = 0; j < 2; ++j) {
        int u = t + j*256;
        int nr = u >> 3, k8 = (u & 7) * 8;
        *(uint4*)&wt[((size_t)(blockIdx.z*4 + g)*256 + nt*64 + nr)*256
                     + kt*64 + k8] = *(const uint4*)&Ls[nr][k8];
    }
}

// ---------------------------------------------------------------------------
// MFMA grouped projection, BM=64 x BN=256 (FULL group per block -> src read
// exactly once: A-traffic 96->48 MB). grid (64 row-tiles, 4 g, 3 z) = 768
// blocks = 3/CU. Wave = 16 rows x 256 cols (acc[16]). Pitch 76/140: all
// LDS b128 frag reads max 2-way (free). Epilogue: two col-half passes, each
// repacks 128 cols and emits the attention swizzle:
//   qs/ks per (b,h): [t16][kcs][lane(l16=seq,quad*8=d)][8]
//   vs    per (b,h): [dt][kc][lane(l16=d,quad*8=key)][8]
// ---------------------------------------------------------------------------
__global__ __launch_bounds__(256, 3) void proj_mfma(
    const float* __restrict__ qin, const float* __restrict__ kin,
    const float* __restrict__ vin,
    const __hip_bfloat16* __restrict__ wt,
    const float* __restrict__ bq, const float* __restrict__ bk,
    const float* __restrict__ bv,
    __hip_bfloat16* __restrict__ qs, __hip_bfloat16* __restrict__ ks_,
    __hip_bfloat16* __restrict__ vs)
{
    const int z = blockIdx.z;
    const float* src; const float* bias;
    if (z == 0)      { src = qin; bias = bq; }
    else if (z == 1) { src = kin; bias = bk; }
    else             { src = vin; bias = bv; }

    const int g    = blockIdx.y;          // group 0..3 (cols g*256..+255)
    const int row0 = blockIdx.x * 64;
    const int b    = row0 >> 11;
    const int s0   = row0 & 2047;

    __shared__ char smem[48640];          // As+Ws main / repack epilogue
    auto As = (__hip_bfloat16 (*)[76])smem;               // 64 x 76 (9.7 KB)
    auto Ws = (__hip_bfloat16 (*)[76])(smem + 9728);      // 256 x 76 (38.9 KB)

    const int t    = threadIdx.x;
    const int wid  = t >> 6;
    const int lane = t & 63;
    const int l16  = lane & 15;
    const int quad = lane >> 4;

    f32x4 acc[16];
    #pragma unroll
    for (int nt = 0; nt < 16; ++nt) acc[nt] = (f32x4){0.f,0.f,0.f,0.f};

    const __hip_bfloat16* wtz = wt + (size_t)(z*4 + g)*65536;

    for (int kt = 0; kt < 4; ++kt) {
        __syncthreads();
        // stage A: 64 rows x 64 k fp32 -> bf16 (coalesced)
        #pragma unroll
        for (int j = 0; j < 4; ++j) {
            int idx = t + j*256;
            int row = idx >> 4, c4 = (idx & 15) * 4;
            float4 f = *(const float4*)&src[(size_t)(row0 + row)*CC + g*256
                                            + kt*64 + c4];
            union { __hip_bfloat16 hh[4]; uint2 u; } pk;
            pk.hh[0] = __float2bfloat16(f.x); pk.hh[1] = __float2bfloat16(f.y);
            pk.hh[2] = __float2bfloat16(f.z); pk.hh[3] = __float2bfloat16(f.w);
            *(uint2*)&As[row][c4] = pk.u;
        }
        // stage W^T: 256 n x 64 k bf16 (coalesced b128)
        #pragma unroll
        for (int j = 0; j < 8; ++j) {
            int idx = t + j*256;
            int n = idx >> 3, k8 = (idx & 7) * 8;
            *(uint4*)&Ws[n][k8] =
                *(const uint4*)&wtz[(size_t)n*256 + kt*64 + k8];
        }
        __syncthreads();
        // MFMA: 32 per wave per kt
        #pragma unroll
        for (int kss = 0; kss < 2; ++kss) {
            bf16x8 af = *(const bf16x8*)&As[wid*16 + l16][kss*32 + quad*8];
            #pragma unroll
            for (int nt = 0; nt < 16; ++nt) {
                bf16x8 wf = *(const bf16x8*)&Ws[nt*16 + l16][kss*32 + quad*8];
                acc[nt] = mfma16(af, wf, acc[nt]);
            }
        }
    }

    float bval[16];
    #pragma unroll
    for (int nt = 0; nt < 16; ++nt) bval[nt] = bias[g*256 + nt*16 + l16];

    // ---- epilogue: two col-half passes (128 cols = head pair each) ----
    #pragma unroll
    for (int p = 0; p < 2; ++p) {
        __syncthreads();   // done with As/Ws (p=0) or previous pass (p=1)
        if (z < 2) {
            const float scale = (z == 0) ? QSC : 1.0f;
            auto Ot = (__hip_bfloat16 (*)[140])smem;   // 64 x 140 (17.9 KB)
            #pragma unroll
            for (int nt8 = 0; nt8 < 8; ++nt8)
                #pragma unroll
                for (int r = 0; r < 4; ++r)
                    Ot[wid*16 + quad*4 + r][nt8*16 + l16] =
                        __float2bfloat16((acc[p*8 + nt8][r] + bval[p*8 + nt8])
                                         * scale);
            __syncthreads();
            __hip_bfloat16* base = (z == 0) ? qs : ks_;
            #pragma unroll
            for (int j = 0; j < 4; ++j) {
                int f = wid + j*4;                 // 16 frag-blocks
                int hl = f >> 3, t16l = (f >> 1) & 3, kcs = f & 1;
                uint4 v = *(const uint4*)&Ot[t16l*16 + l16]
                                            [hl*64 + kcs*32 + quad*8];
                int h = g*4 + p*2 + hl;
                int t16g = (s0 >> 4) + t16l;
                *(uint4*)&base[((size_t)(b*HH + h) << 17)
                               + ((size_t)(t16g*2 + kcs) << 9) + lane*8] = v;
            }
        } else {
            auto Vl = (__hip_bfloat16 (*)[140])smem;   // 128 x 140 transposed
            #pragma unroll
            for (int nt8 = 0; nt8 < 8; ++nt8) {
                union { __hip_bfloat16 hh[4]; uint2 u; } pk;
                #pragma unroll
                for (int r = 0; r < 4; ++r)
                    pk.hh[r] = __float2bfloat16(acc[p*8 + nt8][r]
                                                + bval[p*8 + nt8]);
                *(uint2*)&Vl[nt8*16 + l16][wid*16 + quad*4] = pk.u;
            }
            __syncthreads();
            const int kc0 = s0 >> 5;
            #pragma unroll
            for (int j = 0; j < 4; ++j) {
                int f = wid + j*4;                 // 16 frag-blocks
                int hl = f >> 3, dt = (f >> 1) & 3, kcl = f & 1;
                uint4 v = *(const uint4*)&Vl[hl*64 + dt*16 + l16]
                                            [kcl*32 + quad*8];
                int h = g*4 + p*2 + hl;
                *(uint4*)&vs[((size_t)(b*HH + h) << 17)
                             + ((size_t)(dt*64 + kc0 + kcl) << 9) + lane*8] = v;
            }
        }
    }
}

// ---------------------------------------------------------------------------
// MFMA flash attention: wave = 64 q x 64 keys/iter; block = 2 qsub x 2
// key-halves over 128 q; swizzled coalesced inputs; S^T formulation.
// SOFTWARE-PIPELINED: P double-buffered in LDS; iter kt computes
// S(kt)->exp->P(kt) into buf[kt&1] while PV(kt-1) consumes buf[~kt&1] --
// the P LDS round-trip gets a full iteration of slack. Ps pitch 76 kills
// the previous 8-way b128 bank conflicts (stride 38 dw -> max 2-way, free).
// L via ones^T x P^T MFMA. Combine: Uls aliases Ps buf0 (dead after final
// PV, guarded by barrier). grid (16,16,2) = 512 blocks = 2/CU.
// ---------------------------------------------------------------------------
__global__ __launch_bounds__(256, 2) void attn_mfma(
    const __hip_bfloat16* __restrict__ qs, const __hip_bfloat16* __restrict__ ks_,
    const __hip_bfloat16* __restrict__ vs, float* __restrict__ out)
{
    const int qt = blockIdx.x;   // 0..15 (128-query tile)
    const int h  = blockIdx.y;
    const int b  = blockIdx.z;

    __shared__ __hip_bfloat16 Ps[2][4][64][76];   // double-buffered P, 77.8 KB
    __shared__ float Lls[2][64];
    auto Uls = (float (*)[64][70])&Ps[0][0][0][0]; // combine buf aliases buf0

    const int t    = threadIdx.x;
    const int wid  = t >> 6;
    const int qsub = wid & 1;    // q-subtile (64 q)
    const int kh   = wid >> 1;   // key half (1024 keys)
    const int lane = t & 63;
    const int l16  = lane & 15;
    const int quad = lane >> 4;

    const __hip_bfloat16* qb = qs + ((size_t)(b*HH + h) << 17);
    const __hip_bfloat16* kb = ks_ + ((size_t)(b*HH + h) << 17);
    const __hip_bfloat16* vb = vs + ((size_t)(b*HH + h) << 17);

    const bf16x8 onesv = (bf16x8){16256,16256,16256,16256,
                                  16256,16256,16256,16256};   // bf16 1.0 x8

    bf16x8 qf[4][2];
    #pragma unroll
    for (int mt = 0; mt < 4; ++mt)
        #pragma unroll
        for (int kss = 0; kss < 2; ++kss)
            qf[mt][kss] = *(const bf16x8*)(qb +
                ((size_t)((qt*8 + qsub*4 + mt)*2 + kss) << 9) + lane*8);

    f32x4 O[4][4];
    f32x4 Lfrag[4];
    #pragma unroll
    for (int mt = 0; mt < 4; ++mt) {
        Lfrag[mt] = (f32x4){0.f,0.f,0.f,0.f};
        #pragma unroll
        for (int dt = 0; dt < 4; ++dt) O[mt][dt] = (f32x4){0.f,0.f,0.f,0.f};
    }

    // prefetch K tile 0 of this key half
    bf16x8 kf[4][2];
    #pragma unroll
    for (int nt = 0; nt < 4; ++nt)
        #pragma unroll
        for (int kss = 0; kss < 2; ++kss)
            kf[nt][kss] = *(const bf16x8*)(kb +
                ((size_t)((kh*64 + nt)*2 + kss) << 9) + lane*8);

    for (int kt = 0; kt <= 16; ++kt) {
        const int cur = kt & 1;
        const int prv = cur ^ 1;

        // V^T frags for tile kt-1 (consumed at this iter's PV)
        bf16x8 vfp[4][2];
        if (kt >= 1) {
            #pragma unroll
            for (int dt = 0; dt < 4; ++dt)
                #pragma unroll
                for (int kss = 0; kss < 2; ++kss)
                    vfp[dt][kss] = *(const bf16x8*)(vb +
                        ((size_t)(dt*64 + kh*32 + (kt-1)*2 + kss) << 9) + lane*8);
        }

        if (kt < 16) {
            // S(kt) per 16-key group -> exp -> P(kt) into buf[cur]
            #pragma unroll
            for (int nt = 0; nt < 4; ++nt) {
                f32x4 st[4];
                #pragma unroll
                for (int mt = 0; mt < 4; ++mt) {
                    f32x4 z = (f32x4){0.f,0.f,0.f,0.f};
                    z = mfma16(kf[nt][0], qf[mt][0], z);
                    st[mt] = mfma16(kf[nt][1], qf[mt][1], z);
                }
                #pragma unroll
                for (int mt = 0; mt < 4; ++mt) {
                    float2 e0, e1;
                    e0.x = __builtin_amdgcn_exp2f(st[mt][0]);
                    e0.y = __builtin_amdgcn_exp2f(st[mt][1]);
                    e1.x = __builtin_amdgcn_exp2f(st[mt][2]);
                    e1.y = __builtin_amdgcn_exp2f(st[mt][3]);
                    union { __hip_bfloat162 h2[2]; uint2 u; } pk;
                    pk.h2[0] = __float22bfloat162_rn(e0);
                    pk.h2[1] = __float22bfloat162_rn(e1);
                    *(uint2*)&Ps[cur][wid][mt*16 + l16][nt*16 + quad*4] = pk.u;
                }
            }
            // prefetch K tile kt+1 (kf dead after S)
            if (kt + 1 < 16) {
                #pragma unroll
                for (int nt = 0; nt < 4; ++nt)
                    #pragma unroll
                    for (int kss = 0; kss < 2; ++kss)
                        kf[nt][kss] = *(const bf16x8*)(kb +
                            ((size_t)((kh*64 + (kt+1)*4 + nt)*2 + kss) << 9)
                            + lane*8);
            }
        }

        if (kt >= 1) {
            // PV + L for tile kt-1 from buf[prv] (written last iteration)
            #pragma unroll
            for (int kss = 0; kss < 2; ++kss) {
                bf16x8 pf[4];
                #pragma unroll
                for (int mt = 0; mt < 4; ++mt)
                    pf[mt] = *(const bf16x8*)
                        &Ps[prv][wid][mt*16 + l16][kss*32 + quad*8];
                #pragma unroll
                for (int mt = 0; mt < 4; ++mt) {
                    Lfrag[mt] = mfma16(onesv, pf[mt], Lfrag[mt]);
                    #pragma unroll
                    for (int dt = 0; dt < 4; ++dt)
                        O[mt][dt] = mfma16(vfp[dt][kss], pf[mt], O[mt][dt]);
                }
            }
        }
    }

    // ---- combine the two key halves (Uls aliases Ps buf0) ----
    __syncthreads();   // all waves finished reading Ps
    if (kh == 1) {
        #pragma unroll
        for (int mt = 0; mt < 4; ++mt) {
            if (quad == 0) Lls[qsub][mt*16 + l16] = Lfrag[mt][0];
            #pragma unroll
            for (int dt = 0; dt < 4; ++dt) {
                float4 u4;
                u4.x = O[mt][dt][0]; u4.y = O[mt][dt][1];
                u4.z = O[mt][dt][2]; u4.w = O[mt][dt][3];
                *(float4*)&Uls[qsub][mt*16 + l16][dt*16 + quad*4] = u4;
            }
        }
    }
    __syncthreads();
    if (kh == 0) {
        #pragma unroll
        for (int mt = 0; mt < 4; ++mt) {
            const float inv = 1.0f /
                (1.0f + Lfrag[mt][0] + Lls[qsub][mt*16 + l16]);
            const size_t row = (size_t)b*SS + qt*128 + qsub*64 + mt*16 + l16;
            #pragma unroll
            for (int dt = 0; dt < 4; ++dt) {
                float4 u4 = *(const float4*)
                    &Uls[qsub][mt*16 + l16][dt*16 + quad*4];
                float4 o4;
                o4.x = (O[mt][dt][0] + u4.x) * inv;
                o4.y = (O[mt][dt][1] + u4.y) * inv;
                o4.z = (O[mt][dt][2] + u4.z) * inv;
                o4.w = (O[mt][dt][3] + u4.w) * inv;
                *(float4*)&out[row*CC + h*DDIM + dt*16 + quad*4] = o4;
            }
        }
    }
}

extern "C" void kernel_launch(void* const* d_in, const int* in_sizes, int n_in,
                              void* d_out, int out_size, void* d_ws, size_t ws_size,
                              hipStream_t stream) {
    (void)in_sizes; (void)n_in; (void)out_size; (void)ws_size;
    const float* qin = (const float*)d_in[0];
    const float* kin = (const float*)d_in[1];
    const float* vin = (const float*)d_in[2];
    const float* wq  = (const float*)d_in[3];
    const float* wk  = (const float*)d_in[4];
    const float* wv  = (const float*)d_in[5];
    const float* bq  = (const float*)d_in[6];
    const float* bk  = (const float*)d_in[7];
    const float* bv  = (const float*)d_in[8];

    // ws: qs/ks/vs swizzled bf16 (8 MB each) + wt 1.5 MB
    char* w0 = (char*)d_ws;
    __hip_bfloat16* qs = (__hip_bfloat16*)(w0);
    __hip_bfloat16* ks = (__hip_bfloat16*)(w0 + 8388608);
    __hip_bfloat16* vs = (__hip_bfloat16*)(w0 + 16777216);
    __hip_bfloat16* wt = (__hip_bfloat16*)(w0 + 25165824);
    float* out = (float*)d_out;

    prep_wt<<<dim3(16, 4, 3), 256, 0, stream>>>(wq, wk, wv, wt);
    proj_mfma<<<dim3(64, 4, 3), 256, 0, stream>>>(
        qin, kin, vin, wt, bq, bk, bv, qs, ks, vs);
    attn_mfma<<<dim3(16, 16, 2), 256, 0, stream>>>(qs, ks, vs, out);
}

// Round 13
// 162.082 us; speedup vs baseline: 1.1966x; 1.1966x over previous
//
#include <hip/hip_runtime.h>
#include <hip/hip_bf16.h>

// Problem constants
#define BB 2
#define SS 2048
#define CC 1024
#define HH 16
#define DDIM 64
#define NROWS (BB*SS)   // 4096

// q pre-scale: (1/sqrt(64)) / ln2  -> scores in log2 units, exp2 == exp
#define QSC 0.18033688011112042f

typedef __attribute__((ext_vector_type(8))) short bf16x8;   // 8 bf16 = 4 VGPR
typedef __attribute__((ext_vector_type(4))) float f32x4;

__device__ __forceinline__ f32x4 mfma16(bf16x8 a, bf16x8 b, f32x4 c) {
    return __builtin_amdgcn_mfma_f32_16x16x32_bf16(a, b, c, 0, 0, 0);
}

// NOTE (gfx950 pitfall, measured R12): LDS row pitch MUST keep 16B alignment
// for ds_read_b128 -- pitch 76 (152B rows) made odd rows 8B-misaligned and
// collapsed proj to 3.5% MfmaUtil. Pitch 72 (144B) everywhere.

// ---------------------------------------------------------------------------
// prep_wt: W fp32 [g][k][n] -> bf16 W^T [z*4+g][n][k] via LDS tile transpose.
// ---------------------------------------------------------------------------
__global__ __launch_bounds__(256) void prep_wt(
    const float* __restrict__ wq, const float* __restrict__ wk,
    const float* __restrict__ wv, __hip_bfloat16* __restrict__ wt)
{
    const float* w = blockIdx.z == 0 ? wq : blockIdx.z == 1 ? wk : wv;
    const int g  = blockIdx.y;
    const int kt = blockIdx.x >> 2;
    const int nt = blockIdx.x & 3;
    __shared__ __hip_bfloat16 Ls[64][72];
    const int t = threadIdx.x;
    #pragma unroll
    for (int j = 0; j < 4; ++j) {
        int f4 = t + j*256;
        int row = f4 >> 4, n0 = (f4 & 15) * 4;
        float4 f = *(const float4*)&w[(size_t)g*65536 + (size_t)(kt*64+row)*256
                                      + nt*64 + n0];
        Ls[n0+0][row] = __float2bfloat16(f.x);
        Ls[n0+1][row] = __float2bfloat16(f.y);
        Ls[n0+2][row] = __float2bfloat16(f.z);
        Ls[n0+3][row] = __float2bfloat16(f.w);
    }
    __syncthreads();
    #pragma unroll
    for (int j = 0; j < 2; ++j) {
        int u = t + j*256;
        int nr = u >> 3, k8 = (u & 7) * 8;
        *(uint4*)&wt[((size_t)(blockIdx.z*4 + g)*256 + nt*64 + nr)*256
                     + kt*64 + k8] = *(const uint4*)&Ls[nr][k8];
    }
}

// ---------------------------------------------------------------------------
// MFMA grouped projection, BM=128 x BN=128 (head pair) -- R11 structure
// (proven <48us; R12's BN=256 + pitch-76 variant regressed to 63us).
// Emits attention swizzle:
//   qs/ks per (b,h): [t16][kcs][lane(l16=seq,quad*8=d)][8]
//   vs    per (b,h): [dt][kc][lane(l16=d,quad*8=key)][8]
// grid (32, 8, 3) = 768 blocks.
// ---------------------------------------------------------------------------
__global__ __launch_bounds__(256, 3) void proj_mfma(
    const float* __restrict__ qin, const float* __restrict__ kin,
    const float* __restrict__ vin,
    const __hip_bfloat16* __restrict__ wt,
    const float* __restrict__ bq, const float* __restrict__ bk,
    const float* __restrict__ bv,
    __hip_bfloat16* __restrict__ qs, __hip_bfloat16* __restrict__ ks_,
    __hip_bfloat16* __restrict__ vs)
{
    const int z = blockIdx.z;
    const float* src; const float* bias;
    if (z == 0)      { src = qin; bias = bq; }
    else if (z == 1) { src = kin; bias = bk; }
    else             { src = vin; bias = bv; }

    const int hp   = blockIdx.y;
    const int g    = hp >> 1;
    const int col0 = (hp & 1) * 128;
    const int row0 = blockIdx.x * 128;
    const int b    = row0 >> 11;
    const int s0   = row0 & 2047;

    __shared__ char smem[36864];
    auto As = (__hip_bfloat16 (*)[72])smem;                // 128 x 72
    auto Ws = (__hip_bfloat16 (*)[72])(smem + 18432);      // 128 x 72

    const int t    = threadIdx.x;
    const int wid  = t >> 6;
    const int lane = t & 63;
    const int l16  = lane & 15;
    const int quad = lane >> 4;

    f32x4 acc[2][8];
    #pragma unroll
    for (int mt = 0; mt < 2; ++mt)
        #pragma unroll
        for (int nt = 0; nt < 8; ++nt) acc[mt][nt] = (f32x4){0.f,0.f,0.f,0.f};

    const __hip_bfloat16* wtz = wt + (size_t)(z*4 + g)*65536;

    for (int kt = 0; kt < 4; ++kt) {
        __syncthreads();
        #pragma unroll
        for (int j = 0; j < 8; ++j) {
            int idx = t + j*256;
            int row = idx >> 4, c4 = (idx & 15) * 4;
            float4 f = *(const float4*)&src[(size_t)(row0 + row)*CC + g*256
                                            + kt*64 + c4];
            union { __hip_bfloat16 hh[4]; uint2 u; } pk;
            pk.hh[0] = __float2bfloat16(f.x); pk.hh[1] = __float2bfloat16(f.y);
            pk.hh[2] = __float2bfloat16(f.z); pk.hh[3] = __float2bfloat16(f.w);
            *(uint2*)&As[row][c4] = pk.u;
        }
        #pragma unroll
        for (int j = 0; j < 4; ++j) {
            int idx = t + j*256;
            int n = idx >> 3, k8 = (idx & 7) * 8;
            *(uint4*)&Ws[n][k8] =
                *(const uint4*)&wtz[(size_t)(col0 + n)*256 + kt*64 + k8];
        }
        __syncthreads();
        #pragma unroll
        for (int kss = 0; kss < 2; ++kss) {
            bf16x8 af[2], wf[8];
            #pragma unroll
            for (int mt = 0; mt < 2; ++mt)
                af[mt] = *(const bf16x8*)&As[wid*32 + mt*16 + l16][kss*32 + quad*8];
            #pragma unroll
            for (int nt = 0; nt < 8; ++nt)
                wf[nt] = *(const bf16x8*)&Ws[nt*16 + l16][kss*32 + quad*8];
            #pragma unroll
            for (int mt = 0; mt < 2; ++mt)
                #pragma unroll
                for (int nt = 0; nt < 8; ++nt)
                    acc[mt][nt] = mfma16(af[mt], wf[nt], acc[mt][nt]);
        }
    }

    float bval[8];
    #pragma unroll
    for (int nt = 0; nt < 8; ++nt) bval[nt] = bias[g*256 + col0 + nt*16 + l16];

    __syncthreads();

    if (z < 2) {
        const float scale = (z == 0) ? QSC : 1.0f;
        auto Ot = (__hip_bfloat16 (*)[136])smem;
        #pragma unroll
        for (int mt = 0; mt < 2; ++mt)
            #pragma unroll
            for (int nt = 0; nt < 8; ++nt)
                #pragma unroll
                for (int r = 0; r < 4; ++r)
                    Ot[wid*32 + mt*16 + quad*4 + r][nt*16 + l16] =
                        __float2bfloat16((acc[mt][nt][r] + bval[nt]) * scale);
        __syncthreads();
        __hip_bfloat16* base = (z == 0) ? qs : ks_;
        #pragma unroll
        for (int j = 0; j < 8; ++j) {
            int f = wid + j*4;
            int hl = f >> 4, t16l = (f >> 1) & 7, kcs = f & 1;
            uint4 v = *(const uint4*)&Ot[t16l*16 + l16][hl*64 + kcs*32 + quad*8];
            int h = hp*2 + hl;
            int t16g = (s0 >> 4) + t16l;
            *(uint4*)&base[((size_t)(b*HH + h) << 17)
                           + ((size_t)(t16g*2 + kcs) << 9) + lane*8] = v;
        }
    } else {
        auto Vl = (__hip_bfloat16 (*)[136])smem;
        #pragma unroll
        for (int mt = 0; mt < 2; ++mt)
            #pragma unroll
            for (int nt = 0; nt < 8; ++nt) {
                union { __hip_bfloat16 hh[4]; uint2 u; } pk;
                #pragma unroll
                for (int r = 0; r < 4; ++r)
                    pk.hh[r] = __float2bfloat16(acc[mt][nt][r] + bval[nt]);
                *(uint2*)&Vl[nt*16 + l16][wid*32 + mt*16 + quad*4] = pk.u;
            }
        __syncthreads();
        const int kc0 = s0 >> 5;
        #pragma unroll
        for (int j = 0; j < 8; ++j) {
            int f = wid + j*4;
            int hl = f >> 4, dt = (f >> 2) & 3, kcl = f & 3;
            uint4 v = *(const uint4*)&Vl[hl*64 + dt*16 + l16][kcl*32 + quad*8];
            int h = hp*2 + hl;
            *(uint4*)&vs[((size_t)(b*HH + h) << 17)
                         + ((size_t)(dt*64 + kc0 + kcl) << 9) + lane*8] = v;
        }
    }
}

// ---------------------------------------------------------------------------
// MFMA flash attention: wave = 64 q x 64 keys/iter; block = 2 qsub x 2
// key-halves over 128 q; swizzled coalesced inputs; S^T formulation.
// SOFTWARE-PIPELINED: P double-buffered in LDS; iter kt computes
// S(kt)->exp->P(kt) into buf[kt&1] while PV(kt-1) consumes buf[~kt&1].
// Ps pitch 72: 144B rows keep every b128 frag read 16B-aligned (R12 errata).
// L via ones^T x P^T MFMA. Combine: Uls aliases Ps buf0 (dead after final
// PV, barrier-guarded). grid (16,16,2) = 512 blocks = 2/CU.
// ---------------------------------------------------------------------------
__global__ __launch_bounds__(256, 2) void attn_mfma(
    const __hip_bfloat16* __restrict__ qs, const __hip_bfloat16* __restrict__ ks_,
    const __hip_bfloat16* __restrict__ vs, float* __restrict__ out)
{
    const int qt = blockIdx.x;   // 0..15 (128-query tile)
    const int h  = blockIdx.y;
    const int b  = blockIdx.z;

    __shared__ __hip_bfloat16 Ps[2][4][64][72];   // double-buffered P, 73.7 KB
    __shared__ float Lls[2][64];
    auto Uls = (float (*)[64][68])&Ps[0][0][0][0]; // combine buf aliases buf0

    const int t    = threadIdx.x;
    const int wid  = t >> 6;
    const int qsub = wid & 1;    // q-subtile (64 q)
    const int kh   = wid >> 1;   // key half (1024 keys)
    const int lane = t & 63;
    const int l16  = lane & 15;
    const int quad = lane >> 4;

    const __hip_bfloat16* qb = qs + ((size_t)(b*HH + h) << 17);
    const __hip_bfloat16* kb = ks_ + ((size_t)(b*HH + h) << 17);
    const __hip_bfloat16* vb = vs + ((size_t)(b*HH + h) << 17);

    const bf16x8 onesv = (bf16x8){16256,16256,16256,16256,
                                  16256,16256,16256,16256};   // bf16 1.0 x8

    bf16x8 qf[4][2];
    #pragma unroll
    for (int mt = 0; mt < 4; ++mt)
        #pragma unroll
        for (int kss = 0; kss < 2; ++kss)
            qf[mt][kss] = *(const bf16x8*)(qb +
                ((size_t)((qt*8 + qsub*4 + mt)*2 + kss) << 9) + lane*8);

    f32x4 O[4][4];
    f32x4 Lfrag[4];
    #pragma unroll
    for (int mt = 0; mt < 4; ++mt) {
        Lfrag[mt] = (f32x4){0.f,0.f,0.f,0.f};
        #pragma unroll
        for (int dt = 0; dt < 4; ++dt) O[mt][dt] = (f32x4){0.f,0.f,0.f,0.f};
    }

    // prefetch K tile 0 of this key half
    bf16x8 kf[4][2];
    #pragma unroll
    for (int nt = 0; nt < 4; ++nt)
        #pragma unroll
        for (int kss = 0; kss < 2; ++kss)
            kf[nt][kss] = *(const bf16x8*)(kb +
                ((size_t)((kh*64 + nt)*2 + kss) << 9) + lane*8);

    for (int kt = 0; kt <= 16; ++kt) {
        const int cur = kt & 1;
        const int prv = cur ^ 1;

        // V^T frags for tile kt-1 (consumed at this iter's PV)
        bf16x8 vfp[4][2];
        if (kt >= 1) {
            #pragma unroll
            for (int dt = 0; dt < 4; ++dt)
                #pragma unroll
                for (int kss = 0; kss < 2; ++kss)
                    vfp[dt][kss] = *(const bf16x8*)(vb +
                        ((size_t)(dt*64 + kh*32 + (kt-1)*2 + kss) << 9) + lane*8);
        }

        if (kt < 16) {
            // S(kt) per 16-key group -> exp -> P(kt) into buf[cur]
            #pragma unroll
            for (int nt = 0; nt < 4; ++nt) {
                f32x4 st[4];
                #pragma unroll
                for (int mt = 0; mt < 4; ++mt) {
                    f32x4 z = (f32x4){0.f,0.f,0.f,0.f};
                    z = mfma16(kf[nt][0], qf[mt][0], z);
                    st[mt] = mfma16(kf[nt][1], qf[mt][1], z);
                }
                #pragma unroll
                for (int mt = 0; mt < 4; ++mt) {
                    float2 e0, e1;
                    e0.x = __builtin_amdgcn_exp2f(st[mt][0]);
                    e0.y = __builtin_amdgcn_exp2f(st[mt][1]);
                    e1.x = __builtin_amdgcn_exp2f(st[mt][2]);
                    e1.y = __builtin_amdgcn_exp2f(st[mt][3]);
                    union { __hip_bfloat162 h2[2]; uint2 u; } pk;
                    pk.h2[0] = __float22bfloat162_rn(e0);
                    pk.h2[1] = __float22bfloat162_rn(e1);
                    *(uint2*)&Ps[cur][wid][mt*16 + l16][nt*16 + quad*4] = pk.u;
                }
            }
            // prefetch K tile kt+1 (kf dead after S)
            if (kt + 1 < 16) {
                #pragma unroll
                for (int nt = 0; nt < 4; ++nt)
                    #pragma unroll
                    for (int kss = 0; kss < 2; ++kss)
                        kf[nt][kss] = *(const bf16x8*)(kb +
                            ((size_t)((kh*64 + (kt+1)*4 + nt)*2 + kss) << 9)
                            + lane*8);
            }
        }

        if (kt >= 1) {
            // PV + L for tile kt-1 from buf[prv] (written last iteration)
            #pragma unroll
            for (int kss = 0; kss < 2; ++kss) {
                bf16x8 pf[4];
                #pragma unroll
                for (int mt = 0; mt < 4; ++mt)
                    pf[mt] = *(const bf16x8*)
                        &Ps[prv][wid][mt*16 + l16][kss*32 + quad*8];
                #pragma unroll
                for (int mt = 0; mt < 4; ++mt) {
                    Lfrag[mt] = mfma16(onesv, pf[mt], Lfrag[mt]);
                    #pragma unroll
                    for (int dt = 0; dt < 4; ++dt)
                        O[mt][dt] = mfma16(vfp[dt][kss], pf[mt], O[mt][dt]);
                }
            }
        }
    }

    // ---- combine the two key halves (Uls aliases Ps buf0) ----
    __syncthreads();   // all waves finished reading Ps
    if (kh == 1) {
        #pragma unroll
        for (int mt = 0; mt < 4; ++mt) {
            if (quad == 0) Lls[qsub][mt*16 + l16] = Lfrag[mt][0];
            #pragma unroll
            for (int dt = 0; dt < 4; ++dt) {
                float4 u4;
                u4.x = O[mt][dt][0]; u4.y = O[mt][dt][1];
                u4.z = O[mt][dt][2]; u4.w = O[mt][dt][3];
                *(float4*)&Uls[qsub][mt*16 + l16][dt*16 + quad*4] = u4;
            }
        }
    }
    __syncthreads();
    if (kh == 0) {
        #pragma unroll
        for (int mt = 0; mt < 4; ++mt) {
            const float inv = 1.0f /
                (1.0f + Lfrag[mt][0] + Lls[qsub][mt*16 + l16]);
            const size_t row = (size_t)b*SS + qt*128 + qsub*64 + mt*16 + l16;
            #pragma unroll
            for (int dt = 0; dt < 4; ++dt) {
                float4 u4 = *(const float4*)
                    &Uls[qsub][mt*16 + l16][dt*16 + quad*4];
                float4 o4;
                o4.x = (O[mt][dt][0] + u4.x) * inv;
                o4.y = (O[mt][dt][1] + u4.y) * inv;
                o4.z = (O[mt][dt][2] + u4.z) * inv;
                o4.w = (O[mt][dt][3] + u4.w) * inv;
                *(float4*)&out[row*CC + h*DDIM + dt*16 + quad*4] = o4;
            }
        }
    }
}

extern "C" void kernel_launch(void* const* d_in, const int* in_sizes, int n_in,
                              void* d_out, int out_size, void* d_ws, size_t ws_size,
                              hipStream_t stream) {
    (void)in_sizes; (void)n_in; (void)out_size; (void)ws_size;
    const float* qin = (const float*)d_in[0];
    const float* kin = (const float*)d_in[1];
    const float* vin = (const float*)d_in[2];
    const float* wq  = (const float*)d_in[3];
    const float* wk  = (const float*)d_in[4];
    const float* wv  = (const float*)d_in[5];
    const float* bq  = (const float*)d_in[6];
    const float* bk  = (const float*)d_in[7];
    const float* bv  = (const float*)d_in[8];

    // ws: qs/ks/vs swizzled bf16 (8 MB each) + wt 1.5 MB
    char* w0 = (char*)d_ws;
    __hip_bfloat16* qs = (__hip_bfloat16*)(w0);
    __hip_bfloat16* ks = (__hip_bfloat16*)(w0 + 8388608);
    __hip_bfloat16* vs = (__hip_bfloat16*)(w0 + 16777216);
    __hip_bfloat16* wt = (__hip_bfloat16*)(w0 + 25165824);
    float* out = (float*)d_out;

    prep_wt<<<dim3(16, 4, 3), 256, 0, stream>>>(wq, wk, wv, wt);
    proj_mfma<<<dim3(32, 8, 3), 256, 0, stream>>>(
        qin, kin, vin, wt, bq, bk, bv, qs, ks, vs);
    attn_mfma<<<dim3(16, 16, 2), 256, 0, stream>>>(qs, ks, vs, out);
}